// Round 7
// baseline (192.613 us; speedup 1.0000x reference)
//
#include <hip/hip_runtime.h>
#include <hip/hip_bf16.h>

#define D_MODEL 512
#define NH      8
#define SEQ     2048
#define BATCH   4
#define WINDOW  256
#define ROWS    (BATCH*SEQ)   // 8192

typedef __attribute__((ext_vector_type(8))) short bf16x8;
typedef __attribute__((ext_vector_type(4))) float f32x4;
typedef __hip_bfloat16 bf16;

__device__ __forceinline__ f32x4 mfma16(bf16x8 a, bf16x8 b, f32x4 c) {
    return __builtin_amdgcn_mfma_f32_16x16x32_bf16(a, b, c, 0, 0, 0);
}

__device__ __forceinline__ void gload16(const void* g, void* l) {
    __builtin_amdgcn_global_load_lds((const __attribute__((address_space(1))) void*)g,
                                     (__attribute__((address_space(3))) void*)l, 16, 0, 0);
}

__device__ __forceinline__ unsigned f2bf_u(float f) {
    bf16 h = __float2bfloat16(f);
    return (unsigned)(*(unsigned short*)&h);
}

__device__ __forceinline__ unsigned pack2(float lo, float hi) {
    float2 t; t.x = lo; t.y = hi;
    __hip_bfloat162 h = __float22bfloat162_rn(t);
    return *(unsigned*)&h;
}

// ---------------------------------------------------------------------------
// W transpose+convert: W[512k][512n] f32 -> Wt[512n][512k] bf16 (4 weights)
// ---------------------------------------------------------------------------
__global__ __launch_bounds__(256)
void wconv(const float* __restrict__ W0, const float* __restrict__ W1,
           const float* __restrict__ W2, const float* __restrict__ W3,
           bf16* __restrict__ Wt) {
    const int z = blockIdx.z;
    const float* W = (z == 0) ? W0 : (z == 1) ? W1 : (z == 2) ? W2 : W3;
    bf16* dst = Wt + (size_t)z * D_MODEL * D_MODEL;

    __shared__ float t[64][65];
    const int k0 = blockIdx.x * 64, n0 = blockIdx.y * 64;
    const int tid = threadIdx.x;

    #pragma unroll
    for (int i = 0; i < 16; ++i) {
        const int e = tid + 256 * i, r = e >> 6, c = e & 63;
        t[r][c] = W[(size_t)(k0 + r) * D_MODEL + n0 + c];
    }
    __syncthreads();
    #pragma unroll
    for (int i = 0; i < 16; ++i) {
        const int e = tid + 256 * i, r = e >> 6, c = e & 63;
        dst[(size_t)(n0 + r) * D_MODEL + k0 + c] = __float2bfloat16(t[c][r]);
    }
}

// ---------------------------------------------------------------------------
// Projection GEMM (MFMA, 64x64 tile, BK=64 dbuf, 32KB LDS)
//  X[8192x512] f32 @ Wt^T -> Q/K: [B,H,L,64] bf16;  V (z==2): [B,H,64,L] bf16
// ---------------------------------------------------------------------------
__global__ __launch_bounds__(256)
void proj_mfma(const float* __restrict__ Xq, const float* __restrict__ Xk,
               const float* __restrict__ Xv, const bf16* __restrict__ Wt,
               bf16* __restrict__ Qp, bf16* __restrict__ Kp, bf16* __restrict__ Vp) {
    const int z = blockIdx.z;
    const float* X = (z == 0) ? Xq : (z == 1) ? Xk : Xv;
    const bf16* W = Wt + (size_t)z * D_MODEL * D_MODEL;   // [n][k] bf16
    bf16* outp = (z == 0) ? Qp : (z == 1) ? Kp : Vp;

    __shared__ bf16 Asw[2][64 * 64];
    __shared__ bf16 Bsw[2][64 * 64];

    const int tid = threadIdx.x;
    const int lane = tid & 63, w = tid >> 6;
    const int wr = w >> 1, wc = w & 1;
    const int row0 = blockIdx.x * 64, col0 = blockIdx.y * 64;
    const int g = lane >> 4, m16 = lane & 15;

    f32x4 acc[2][2] = {};
    float4 a0[2], a1[2];

    auto stageB = [&](int buf, int k0) {
        #pragma unroll
        for (int i = 0; i < 2; ++i) {
            const int chunk = i * 256 + w * 64 + lane;
            const int n = chunk >> 3, s = chunk & 7;
            gload16(W + (size_t)(col0 + n) * D_MODEL + k0 + ((s ^ (n & 7)) * 8),
                    &Bsw[buf][(i * 256 + w * 64) * 8]);
        }
    };
    auto loadA = [&](int k0) {
        #pragma unroll
        for (int i = 0; i < 2; ++i) {
            const int chunk = i * 256 + tid;
            const int m = chunk >> 3, s = chunk & 7;
            const float* gp = X + (size_t)(row0 + m) * D_MODEL + k0 + ((s ^ (m & 7)) * 8);
            a0[i] = *(const float4*)gp;
            a1[i] = *(const float4*)(gp + 4);
        }
    };
    auto writeA = [&](int buf) {
        #pragma unroll
        for (int i = 0; i < 2; ++i) {
            const int chunk = i * 256 + tid;
            const int m = chunk >> 3, s = chunk & 7;
            int4 pk;
            pk.x = pack2(a0[i].x, a0[i].y);
            pk.y = pack2(a0[i].z, a0[i].w);
            pk.z = pack2(a1[i].x, a1[i].y);
            pk.w = pack2(a1[i].z, a1[i].w);
            *(int4*)&Asw[buf][m * 64 + s * 8] = pk;
        }
    };

    stageB(0, 0);
    loadA(0);
    writeA(0);
    __syncthreads();

    int cur = 0;
    for (int step = 0; step < 8; ++step) {
        const int k0n = (step + 1) * 64;
        if (step < 7) { stageB(cur ^ 1, k0n); loadA(k0n); }

        #pragma unroll
        for (int c = 0; c < 2; ++c) {
            bf16x8 af[2], bfr[2];
            #pragma unroll
            for (int mi = 0; mi < 2; ++mi) {
                const int m = wr * 32 + mi * 16 + m16;
                const int slot = (c * 4 + g) ^ (m & 7);
                af[mi] = *(const bf16x8*)&Asw[cur][m * 64 + slot * 8];
            }
            #pragma unroll
            for (int ni = 0; ni < 2; ++ni) {
                const int n = wc * 32 + ni * 16 + m16;
                const int slot = (c * 4 + g) ^ (n & 7);
                bfr[ni] = *(const bf16x8*)&Bsw[cur][n * 64 + slot * 8];
            }
            #pragma unroll
            for (int mi = 0; mi < 2; ++mi)
                #pragma unroll
                for (int ni = 0; ni < 2; ++ni)
                    acc[mi][ni] = mfma16(af[mi], bfr[ni], acc[mi][ni]);
        }

        if (step < 7) {
            writeA(cur ^ 1);
            __syncthreads();
        }
        cur ^= 1;
    }

    if (z < 2) {
        #pragma unroll
        for (int mi = 0; mi < 2; ++mi)
            #pragma unroll
            for (int ni = 0; ni < 2; ++ni) {
                const int c = col0 + wc * 32 + ni * 16 + m16;
                const int h = c >> 6, d = c & 63;
                #pragma unroll
                for (int reg = 0; reg < 4; ++reg) {
                    const int r = row0 + wr * 32 + mi * 16 + g * 4 + reg;
                    const int b = r >> 11, l = r & (SEQ - 1);
                    outp[(((size_t)b * NH + h) * SEQ + l) * 64 + d] =
                        __float2bfloat16(acc[mi][ni][reg]);
                }
            }
    } else {
        #pragma unroll
        for (int mi = 0; mi < 2; ++mi)
            #pragma unroll
            for (int ni = 0; ni < 2; ++ni) {
                const int c = col0 + wc * 32 + ni * 16 + m16;
                const int h = c >> 6, d = c & 63;
                const int r = row0 + wr * 32 + mi * 16 + g * 4;
                const int b = r >> 11, l = r & (SEQ - 1);
                uint2 pv;
                pv.x = pack2(acc[mi][ni][0], acc[mi][ni][1]);
                pv.y = pack2(acc[mi][ni][2], acc[mi][ni][3]);
                *(uint2*)&outp[(((size_t)b * NH + h) * 64 + d) * SEQ + l] = pv;
            }
    }
}

// ---------------------------------------------------------------------------
// Banded flash attention: NO K/V LDS staging — fragments loaded directly
// from global (L2-resident). Each wave owns 16 queries; only P is in LDS
// (per-wave 2KB region). No barriers in the K-tile loop.
// ---------------------------------------------------------------------------
__global__ __launch_bounds__(256)
void attn_mfma(const bf16* __restrict__ Qp, const bf16* __restrict__ Kp,
               const bf16* __restrict__ Vp, bf16* __restrict__ ctx) {
    __shared__ bf16 Ps[4][16 * 64];

    const int bh = blockIdx.y, b = bh >> 3, h = bh & 7;
    const int tid = threadIdx.x;
    const int lane = tid & 63, w = tid >> 6;
    const int g = lane >> 4, m16 = lane & 15;
    const int q0w = blockIdx.x * 64 + w * 16;       // this wave's 16 queries

    const size_t kvbase = (size_t)bh * SEQ * 64;    // Qp/Kp [bh][l][64]
    const size_t vtbase = (size_t)bh * 64 * SEQ;    // Vp    [bh][d][l]

    // Q fragments direct from global
    bf16x8 qf[2];
    #pragma unroll
    for (int c = 0; c < 2; ++c)
        qf[c] = *(const bf16x8*)(Qp + kvbase + (size_t)(q0w + m16) * 64 + c * 32 + g * 8);

    f32x4 o[4] = {};
    float rs = 0.f;
    const int qg = q0w + m16;

    int klo = q0w - (WINDOW - 1); if (klo < 0) klo = 0;
    const int kt0 = klo >> 6, kt1 = q0w >> 6;

    for (int kt = kt0; kt <= kt1; ++kt) {
        const int k0 = kt * 64;

        // S^T[f] = K_f . Q^T ; K fragments direct from global
        f32x4 st[4] = {};
        #pragma unroll
        for (int c = 0; c < 2; ++c) {
            bf16x8 kf[4];
            #pragma unroll
            for (int f = 0; f < 4; ++f)
                kf[f] = *(const bf16x8*)(Kp + kvbase +
                         (size_t)(k0 + f * 16 + m16) * 64 + c * 32 + g * 8);
            #pragma unroll
            for (int f = 0; f < 4; ++f)
                st[f] = mfma16(kf[f], qf[c], st[f]);
        }

        // mask + exp + rowsum; pack P into wave-own LDS region
        const int masktype = (kt == kt1) ? 1 : ((k0 < q0w - 240) ? 2 : 0);
        #pragma unroll
        for (int f = 0; f < 4; ++f) {
            float p[4];
            #pragma unroll
            for (int reg = 0; reg < 4; ++reg) {
                const int kg = k0 + f * 16 + g * 4 + reg;
                bool valid = (masktype == 0) || (masktype == 1 ? (kg <= qg)
                                                              : (kg >= qg - (WINDOW - 1)));
                p[reg] = valid ? __expf(st[f][reg] * 0.125f) : 0.f;
                rs += p[reg];
            }
            uint2 pkv;
            pkv.x = pack2(p[0], p[1]);
            pkv.y = pack2(p[2], p[3]);
            const int slot = (f * 2 + (g >> 1)) ^ (m16 & 7);
            *(uint2*)&Ps[w][m16 * 64 + slot * 8 + (g & 1) * 4] = pkv;
        }

        // O += P . V^T ; V fragments direct from global
        #pragma unroll
        for (int c = 0; c < 2; ++c) {
            const bf16x8 pf =
                *(const bf16x8*)&Ps[w][m16 * 64 + (((c * 4 + g) ^ (m16 & 7)) * 8)];
            #pragma unroll
            for (int f2 = 0; f2 < 4; ++f2) {
                const bf16x8 vf = *(const bf16x8*)(Vp + vtbase +
                         (size_t)(f2 * 16 + m16) * SEQ + k0 + c * 32 + g * 8);
                o[f2] = mfma16(pf, vf, o[f2]);
            }
        }
    }

    // denominators: sum partials across the four 16-lane groups
    rs += __shfl_xor(rs, 16, 64);
    rs += __shfl_xor(rs, 32, 64);
    const float inv = 1.0f / rs;
    float invr[4];
    #pragma unroll
    for (int reg = 0; reg < 4; ++reg)
        invr[reg] = __shfl(inv, g * 4 + reg, 64);

    #pragma unroll
    for (int f2 = 0; f2 < 4; ++f2) {
        const int d = f2 * 16 + m16;
        #pragma unroll
        for (int reg = 0; reg < 4; ++reg) {
            const int qrow = q0w + g * 4 + reg;
            ctx[((size_t)b * SEQ + qrow) * D_MODEL + h * 64 + d] =
                __float2bfloat16(o[f2][reg] * invr[reg]);
        }
    }
}

// ---------------------------------------------------------------------------
// fc GEMM (MFMA, 64x64 tile, BK=64 dbuf): ctx bf16 @ Wfc^T + resid -> out f32
// ---------------------------------------------------------------------------
__global__ __launch_bounds__(256)
void fc_mfma(const bf16* __restrict__ ctx, const bf16* __restrict__ Wt,
             const float* __restrict__ resid, float* __restrict__ out) {
    __shared__ bf16 Asw[2][64 * 64];
    __shared__ bf16 Bsw[2][64 * 64];

    const int tid = threadIdx.x;
    const int lane = tid & 63, w = tid >> 6;
    const int wr = w >> 1, wc = w & 1;
    const int row0 = blockIdx.x * 64, col0 = blockIdx.y * 64;
    const int g = lane >> 4, m16 = lane & 15;

    f32x4 acc[2][2] = {};

    auto stage = [&](int buf, int k0) {
        #pragma unroll
        for (int i = 0; i < 2; ++i) {
            const int chunk = i * 256 + w * 64 + lane;
            const int m = chunk >> 3, s = chunk & 7;
            gload16(ctx + (size_t)(row0 + m) * D_MODEL + k0 + ((s ^ (m & 7)) * 8),
                    &Asw[buf][(i * 256 + w * 64) * 8]);
            gload16(Wt + (size_t)(col0 + m) * D_MODEL + k0 + ((s ^ (m & 7)) * 8),
                    &Bsw[buf][(i * 256 + w * 64) * 8]);
        }
    };

    stage(0, 0);
    __syncthreads();

    int cur = 0;
    for (int step = 0; step < 8; ++step) {
        if (step < 7) stage(cur ^ 1, (step + 1) * 64);

        #pragma unroll
        for (int c = 0; c < 2; ++c) {
            bf16x8 af[2], bfr[2];
            #pragma unroll
            for (int mi = 0; mi < 2; ++mi) {
                const int m = wr * 32 + mi * 16 + m16;
                const int slot = (c * 4 + g) ^ (m & 7);
                af[mi] = *(const bf16x8*)&Asw[cur][m * 64 + slot * 8];
            }
            #pragma unroll
            for (int ni = 0; ni < 2; ++ni) {
                const int n = wc * 32 + ni * 16 + m16;
                const int slot = (c * 4 + g) ^ (n & 7);
                bfr[ni] = *(const bf16x8*)&Bsw[cur][n * 64 + slot * 8];
            }
            #pragma unroll
            for (int mi = 0; mi < 2; ++mi)
                #pragma unroll
                for (int ni = 0; ni < 2; ++ni)
                    acc[mi][ni] = mfma16(af[mi], bfr[ni], acc[mi][ni]);
        }

        if (step < 7) __syncthreads();
        cur ^= 1;
    }

    #pragma unroll
    for (int mi = 0; mi < 2; ++mi)
        #pragma unroll
        for (int ni = 0; ni < 2; ++ni) {
            const int c = col0 + wc * 32 + ni * 16 + m16;
            #pragma unroll
            for (int reg = 0; reg < 4; ++reg) {
                const int r = row0 + wr * 32 + mi * 16 + g * 4 + reg;
                out[(size_t)r * D_MODEL + c] = acc[mi][ni][reg] + resid[(size_t)r * D_MODEL + c];
            }
        }
}

// ---------------------------------------------------------------------------
// LayerNorm in-place over last dim (512)
// ---------------------------------------------------------------------------
__global__ __launch_bounds__(256)
void ln_kernel(float* __restrict__ out) {
    const int row = blockIdx.x;
    float* p = out + (size_t)row * D_MODEL;
    const int tid = threadIdx.x;

    float2 x = *(float2*)&p[tid * 2];
    float s  = x.x + x.y;
    float s2 = x.x * x.x + x.y * x.y;
    #pragma unroll
    for (int m = 1; m < 64; m <<= 1) {
        s  += __shfl_xor(s,  m, 64);
        s2 += __shfl_xor(s2, m, 64);
    }
    __shared__ float sa[4], sb[4];
    const int w = tid >> 6;
    if ((tid & 63) == 0) { sa[w] = s; sb[w] = s2; }
    __syncthreads();
    s  = sa[0] + sa[1] + sa[2] + sa[3];
    s2 = sb[0] + sb[1] + sb[2] + sb[3];

    const float mean = s * (1.0f / D_MODEL);
    const float var  = s2 * (1.0f / D_MODEL) - mean * mean;
    const float rstd = rsqrtf(var + 1e-5f);

    x.x = (x.x - mean) * rstd;
    x.y = (x.y - mean) * rstd;
    *(float2*)&p[tid * 2] = x;
}

// ---------------------------------------------------------------------------
extern "C" void kernel_launch(void* const* d_in, const int* in_sizes, int n_in,
                              void* d_out, int out_size, void* d_ws, size_t ws_size,
                              hipStream_t stream) {
    const float* inQ = (const float*)d_in[0];
    const float* inK = (const float*)d_in[1];
    const float* inV = (const float*)d_in[2];
    const float* WQ  = (const float*)d_in[3];
    const float* WK  = (const float*)d_in[4];
    const float* WV  = (const float*)d_in[5];
    const float* Wfc = (const float*)d_in[6];
    float* out = (float*)d_out;

    bf16* ws = (bf16*)d_ws;
    const size_t WSZ = (size_t)D_MODEL * D_MODEL;       // 262144
    const size_t NE  = (size_t)BATCH * NH * SEQ * 64;   // 4194304
    bf16* Wt   = ws;
    bf16* Qp   = ws + 4 * WSZ;
    bf16* Kp   = Qp + NE;
    bf16* Vp   = Kp + NE;
    bf16* ctxb = Vp + NE;

    wconv<<<dim3(8, 8, 4), 256, 0, stream>>>(WQ, WK, WV, Wfc, Wt);
    proj_mfma<<<dim3(ROWS / 64, D_MODEL / 64, 3), 256, 0, stream>>>(
        inQ, inK, inV, Wt, Qp, Kp, Vp);
    attn_mfma<<<dim3(SEQ / 64, BATCH * NH), 256, 0, stream>>>(Qp, Kp, Vp, ctxb);
    fc_mfma<<<dim3(ROWS / 64, D_MODEL / 64), 256, 0, stream>>>(
        ctxb, Wt + 3 * WSZ, inQ, out);
    ln_kernel<<<ROWS, 256, 0, stream>>>(out);
}

// Round 8
// 168.933 us; speedup vs baseline: 1.1402x; 1.1402x over previous
//
#include <hip/hip_runtime.h>
#include <hip/hip_bf16.h>

#define D_MODEL 512
#define NH      8
#define SEQ     2048
#define BATCH   4
#define WINDOW  256
#define ROWS    (BATCH*SEQ)   // 8192

typedef __attribute__((ext_vector_type(8))) short bf16x8;
typedef __attribute__((ext_vector_type(4))) float f32x4;
typedef __hip_bfloat16 bf16;

__device__ __forceinline__ f32x4 mfma16(bf16x8 a, bf16x8 b, f32x4 c) {
    return __builtin_amdgcn_mfma_f32_16x16x32_bf16(a, b, c, 0, 0, 0);
}

__device__ __forceinline__ void gload16(const void* g, void* l) {
    __builtin_amdgcn_global_load_lds((const __attribute__((address_space(1))) void*)g,
                                     (__attribute__((address_space(3))) void*)l, 16, 0, 0);
}

__device__ __forceinline__ unsigned pack2(float lo, float hi) {
    float2 t; t.x = lo; t.y = hi;
    __hip_bfloat162 h = __float22bfloat162_rn(t);
    return *(unsigned*)&h;
}

// ---------------------------------------------------------------------------
// W transpose+convert: W[512k][512n] f32 -> Wt[512n][512k] bf16 (4 weights)
// ---------------------------------------------------------------------------
__global__ __launch_bounds__(256)
void wconv(const float* __restrict__ W0, const float* __restrict__ W1,
           const float* __restrict__ W2, const float* __restrict__ W3,
           bf16* __restrict__ Wt) {
    const int z = blockIdx.z;
    const float* W = (z == 0) ? W0 : (z == 1) ? W1 : (z == 2) ? W2 : W3;
    bf16* dst = Wt + (size_t)z * D_MODEL * D_MODEL;

    __shared__ float t[64][65];
    const int k0 = blockIdx.x * 64, n0 = blockIdx.y * 64;
    const int tid = threadIdx.x;

    #pragma unroll
    for (int i = 0; i < 16; ++i) {
        const int e = tid + 256 * i, r = e >> 6, c = e & 63;
        t[r][c] = W[(size_t)(k0 + r) * D_MODEL + n0 + c];
    }
    __syncthreads();
    #pragma unroll
    for (int i = 0; i < 16; ++i) {
        const int e = tid + 256 * i, r = e >> 6, c = e & 63;
        dst[(size_t)(n0 + r) * D_MODEL + k0 + c] = __float2bfloat16(t[c][r]);
    }
}

// ---------------------------------------------------------------------------
// Projection GEMM: 128x128 tile, BK=32 dbuf (32KB), 512 threads = 8 waves.
// Wave owns 64x32 (acc 4x2). X[8192x512] f32 @ Wt^T.
//  -> Q/K: [B,H,L,64] bf16;  V (z==2): [B,H,64,L] bf16
// ---------------------------------------------------------------------------
__global__ __launch_bounds__(512)
void proj_mfma(const float* __restrict__ Xq, const float* __restrict__ Xk,
               const float* __restrict__ Xv, const bf16* __restrict__ Wt,
               bf16* __restrict__ Qp, bf16* __restrict__ Kp, bf16* __restrict__ Vp) {
    const int z = blockIdx.z;
    const float* X = (z == 0) ? Xq : (z == 1) ? Xk : Xv;
    const bf16* W = Wt + (size_t)z * D_MODEL * D_MODEL;   // [n][k] bf16
    bf16* outp = (z == 0) ? Qp : (z == 1) ? Kp : Vp;

    __shared__ bf16 Asw[2][128 * 32];
    __shared__ bf16 Bsw[2][128 * 32];

    const int tid = threadIdx.x;
    const int lane = tid & 63, w = tid >> 6;
    const int wr = w >> 2, wc = w & 3;          // 2 x 4 wave grid
    const int row0 = blockIdx.x * 128, col0 = blockIdx.y * 128;
    const int g = lane >> 4, m16 = lane & 15;

    f32x4 acc[4][2] = {};
    float4 a0, a1;

    // one 16B chunk per thread per operand: m = tid>>2, s = tid&3
    auto stageB = [&](int buf, int k0) {
        const int n = tid >> 2, s = tid & 3;
        gload16(W + (size_t)(col0 + n) * D_MODEL + k0 + ((s ^ (n & 3)) * 8),
                &Bsw[buf][tid * 8]);
    };
    auto loadA = [&](int k0) {
        const int m = tid >> 2, s = tid & 3;
        const float* gp = X + (size_t)(row0 + m) * D_MODEL + k0 + ((s ^ (m & 3)) * 8);
        a0 = *(const float4*)gp;
        a1 = *(const float4*)(gp + 4);
    };
    auto writeA = [&](int buf) {
        const int m = tid >> 2, s = tid & 3;
        int4 pk;
        pk.x = pack2(a0.x, a0.y);
        pk.y = pack2(a0.z, a0.w);
        pk.z = pack2(a1.x, a1.y);
        pk.w = pack2(a1.z, a1.w);
        *(int4*)&Asw[buf][m * 32 + s * 8] = pk;
    };

    stageB(0, 0);
    loadA(0);
    writeA(0);
    __syncthreads();

    int cur = 0;
    for (int step = 0; step < 16; ++step) {
        const int k0n = (step + 1) * 32;
        if (step < 15) { stageB(cur ^ 1, k0n); loadA(k0n); }

        bf16x8 af[4], bfr[2];
        #pragma unroll
        for (int mi = 0; mi < 4; ++mi) {
            const int m = wr * 64 + mi * 16 + m16;
            af[mi] = *(const bf16x8*)&Asw[cur][m * 32 + ((g ^ (m & 3)) * 8)];
        }
        #pragma unroll
        for (int ni = 0; ni < 2; ++ni) {
            const int n = wc * 32 + ni * 16 + m16;
            bfr[ni] = *(const bf16x8*)&Bsw[cur][n * 32 + ((g ^ (n & 3)) * 8)];
        }
        #pragma unroll
        for (int mi = 0; mi < 4; ++mi)
            #pragma unroll
            for (int ni = 0; ni < 2; ++ni)
                acc[mi][ni] = mfma16(af[mi], bfr[ni], acc[mi][ni]);

        if (step < 15) {
            writeA(cur ^ 1);
            __syncthreads();
        }
        cur ^= 1;
    }

    if (z < 2) {
        #pragma unroll
        for (int mi = 0; mi < 4; ++mi)
            #pragma unroll
            for (int ni = 0; ni < 2; ++ni) {
                const int c = col0 + wc * 32 + ni * 16 + m16;
                const int h = c >> 6, d = c & 63;
                #pragma unroll
                for (int reg = 0; reg < 4; ++reg) {
                    const int r = row0 + wr * 64 + mi * 16 + g * 4 + reg;
                    const int b = r >> 11, l = r & (SEQ - 1);
                    outp[(((size_t)b * NH + h) * SEQ + l) * 64 + d] =
                        __float2bfloat16(acc[mi][ni][reg]);
                }
            }
    } else {
        #pragma unroll
        for (int mi = 0; mi < 4; ++mi)
            #pragma unroll
            for (int ni = 0; ni < 2; ++ni) {
                const int c = col0 + wc * 32 + ni * 16 + m16;
                const int h = c >> 6, d = c & 63;
                const int r = row0 + wr * 64 + mi * 16 + g * 4;
                const int b = r >> 11, l = r & (SEQ - 1);
                uint2 pv;
                pv.x = pack2(acc[mi][ni][0], acc[mi][ni][1]);
                pv.y = pack2(acc[mi][ni][2], acc[mi][ni][3]);
                *(uint2*)&outp[(((size_t)b * NH + h) * 64 + d) * SEQ + l] = pv;
            }
    }
}

// ---------------------------------------------------------------------------
// Banded flash attention (MFMA, K/V dbuf prefetch, gload16 staging).
// Q-staging buffer reused for P after Q fragments are hoisted (per-wave
// regions disjoint in both uses).  [round-6 measured version, unchanged]
// ---------------------------------------------------------------------------
__global__ __launch_bounds__(256)
void attn_mfma(const bf16* __restrict__ Qp, const bf16* __restrict__ Kp,
               const bf16* __restrict__ Vp, bf16* __restrict__ ctx) {
    __shared__ bf16 QP[64 * 64];        // Q staging, then P (per-wave regions)
    __shared__ bf16 Ks[2][64 * 64];
    __shared__ bf16 Vt[2][64 * 64];

    const int bh = blockIdx.y, b = bh >> 3, h = bh & 7;
    const int q0 = blockIdx.x * 64;
    const int tid = threadIdx.x;
    const int lane = tid & 63, w = tid >> 6;
    const int g = lane >> 4, m16 = lane & 15;

    const size_t kvbase = (size_t)bh * SEQ * 64;   // Qp/Kp [bh][l][64]
    const size_t vtbase = (size_t)bh * 64 * SEQ;   // Vp    [bh][d][l]

    auto stageKV = [&](int buf, int k0) {
        #pragma unroll
        for (int i = 0; i < 2; ++i) {
            const int chunk = i * 256 + tid;
            const int r = chunk >> 3, s = chunk & 7;
            gload16(Kp + kvbase + (size_t)(k0 + r) * 64 + ((s ^ (r & 7)) * 8),
                    &Ks[buf][(i * 256 + w * 64) * 8]);
            gload16(Vp + vtbase + (size_t)r * SEQ + k0 + ((s ^ (r & 7)) * 8),
                    &Vt[buf][(i * 256 + w * 64) * 8]);
        }
    };

    int klo = q0 - (WINDOW - 1); if (klo < 0) klo = 0;
    const int kt0 = klo >> 6, kt1 = q0 >> 6;

    // prologue: Q + first K/V tile
    #pragma unroll
    for (int i = 0; i < 2; ++i) {
        const int chunk = i * 256 + tid;
        const int r = chunk >> 3, s = chunk & 7;
        gload16(Qp + kvbase + (size_t)(q0 + r) * 64 + ((s ^ (r & 7)) * 8),
                &QP[(i * 256 + w * 64) * 8]);
    }
    stageKV(0, kt0 * 64);
    __syncthreads();

    // hoisted Q fragments (B operand): row = w*16+m16 (wave's own region)
    bf16x8 qf[2];
    #pragma unroll
    for (int c = 0; c < 2; ++c) {
        const int r = w * 16 + m16;
        qf[c] = *(const bf16x8*)&QP[r * 64 + (((c * 4 + g) ^ (m16 & 7)) * 8)];
    }

    f32x4 o[4] = {};
    float rs = 0.f;
    const int qg = q0 + w * 16 + m16;

    int cur = 0;
    for (int kt = kt0; kt <= kt1; ++kt) {
        const int k0 = kt * 64;
        if (kt < kt1) stageKV(cur ^ 1, (kt + 1) * 64);

        // S^T[f] = K_f . Q^T
        f32x4 st[4] = {};
        #pragma unroll
        for (int c = 0; c < 2; ++c) {
            bf16x8 kf[4];
            #pragma unroll
            for (int f = 0; f < 4; ++f) {
                const int r = f * 16 + m16;
                kf[f] = *(const bf16x8*)&Ks[cur][r * 64 + (((c * 4 + g) ^ (m16 & 7)) * 8)];
            }
            #pragma unroll
            for (int f = 0; f < 4; ++f)
                st[f] = mfma16(kf[f], qf[c], st[f]);
        }

        // mask + exp + rowsum; pack P into wave-own region of QP
        const int masktype = (k0 == q0) ? 1 : ((k0 < q0 - 192) ? 2 : 0);
        #pragma unroll
        for (int f = 0; f < 4; ++f) {
            float p[4];
            #pragma unroll
            for (int reg = 0; reg < 4; ++reg) {
                const int kg = k0 + f * 16 + g * 4 + reg;
                bool valid = (masktype == 0) || (masktype == 1 ? (kg <= qg)
                                                              : (kg >= qg - (WINDOW - 1)));
                p[reg] = valid ? __expf(st[f][reg] * 0.125f) : 0.f;
                rs += p[reg];
            }
            uint2 pkv;
            pkv.x = pack2(p[0], p[1]);
            pkv.y = pack2(p[2], p[3]);
            const int slot = (f * 2 + (g >> 1)) ^ (m16 & 7);
            *(uint2*)&QP[w * 1024 + m16 * 64 + slot * 8 + (g & 1) * 4] = pkv;
        }

        // O += P . V^T
        #pragma unroll
        for (int c = 0; c < 2; ++c) {
            const bf16x8 pf =
                *(const bf16x8*)&QP[w * 1024 + m16 * 64 + (((c * 4 + g) ^ (m16 & 7)) * 8)];
            #pragma unroll
            for (int f2 = 0; f2 < 4; ++f2) {
                const int r = f2 * 16 + m16;
                const bf16x8 vf =
                    *(const bf16x8*)&Vt[cur][r * 64 + (((c * 4 + g) ^ (m16 & 7)) * 8)];
                o[f2] = mfma16(pf, vf, o[f2]);
            }
        }

        if (kt < kt1) __syncthreads();
        cur ^= 1;
    }

    // denominators
    rs += __shfl_xor(rs, 16, 64);
    rs += __shfl_xor(rs, 32, 64);
    const float inv = 1.0f / rs;
    float invr[4];
    #pragma unroll
    for (int reg = 0; reg < 4; ++reg)
        invr[reg] = __shfl(inv, g * 4 + reg, 64);

    #pragma unroll
    for (int f2 = 0; f2 < 4; ++f2) {
        const int d = f2 * 16 + m16;
        #pragma unroll
        for (int reg = 0; reg < 4; ++reg) {
            const int qrow = w * 16 + g * 4 + reg;
            ctx[((size_t)b * SEQ + q0 + qrow) * D_MODEL + h * 64 + d] =
                __float2bfloat16(o[f2][reg] * invr[reg]);
        }
    }
}

// ---------------------------------------------------------------------------
// fc GEMM: 128x128, BK=32 dbuf, 512 threads/8 waves: ctx bf16 @ Wfc^T + resid
// ---------------------------------------------------------------------------
__global__ __launch_bounds__(512)
void fc_mfma(const bf16* __restrict__ ctx, const bf16* __restrict__ Wt,
             const float* __restrict__ resid, float* __restrict__ out) {
    __shared__ bf16 Asw[2][128 * 32];
    __shared__ bf16 Bsw[2][128 * 32];

    const int tid = threadIdx.x;
    const int lane = tid & 63, w = tid >> 6;
    const int wr = w >> 2, wc = w & 3;
    const int row0 = blockIdx.x * 128, col0 = blockIdx.y * 128;
    const int g = lane >> 4, m16 = lane & 15;

    f32x4 acc[4][2] = {};

    auto stage = [&](int buf, int k0) {
        const int m = tid >> 2, s = tid & 3;
        gload16(ctx + (size_t)(row0 + m) * D_MODEL + k0 + ((s ^ (m & 3)) * 8),
                &Asw[buf][tid * 8]);
        gload16(Wt + (size_t)(col0 + m) * D_MODEL + k0 + ((s ^ (m & 3)) * 8),
                &Bsw[buf][tid * 8]);
    };

    stage(0, 0);
    __syncthreads();

    int cur = 0;
    for (int step = 0; step < 16; ++step) {
        if (step < 15) stage(cur ^ 1, (step + 1) * 32);

        bf16x8 af[4], bfr[2];
        #pragma unroll
        for (int mi = 0; mi < 4; ++mi) {
            const int m = wr * 64 + mi * 16 + m16;
            af[mi] = *(const bf16x8*)&Asw[cur][m * 32 + ((g ^ (m & 3)) * 8)];
        }
        #pragma unroll
        for (int ni = 0; ni < 2; ++ni) {
            const int n = wc * 32 + ni * 16 + m16;
            bfr[ni] = *(const bf16x8*)&Bsw[cur][n * 32 + ((g ^ (n & 3)) * 8)];
        }
        #pragma unroll
        for (int mi = 0; mi < 4; ++mi)
            #pragma unroll
            for (int ni = 0; ni < 2; ++ni)
                acc[mi][ni] = mfma16(af[mi], bfr[ni], acc[mi][ni]);

        if (step < 15) __syncthreads();
        cur ^= 1;
    }

    // Asw staging area of tid>>2 mapping: m ranges over 128 rows; within-wave
    // lanes are consecutive chunks so gload dst is wave-uniform+lane*16 (ok).
    #pragma unroll
    for (int mi = 0; mi < 4; ++mi)
        #pragma unroll
        for (int ni = 0; ni < 2; ++ni) {
            const int c = col0 + wc * 32 + ni * 16 + m16;
            #pragma unroll
            for (int reg = 0; reg < 4; ++reg) {
                const int r = row0 + wr * 64 + mi * 16 + g * 4 + reg;
                out[(size_t)r * D_MODEL + c] = acc[mi][ni][reg] + resid[(size_t)r * D_MODEL + c];
            }
        }
}

// ---------------------------------------------------------------------------
// LayerNorm in-place over last dim (512)
// ---------------------------------------------------------------------------
__global__ __launch_bounds__(256)
void ln_kernel(float* __restrict__ out) {
    const int row = blockIdx.x;
    float* p = out + (size_t)row * D_MODEL;
    const int tid = threadIdx.x;

    float2 x = *(float2*)&p[tid * 2];
    float s  = x.x + x.y;
    float s2 = x.x * x.x + x.y * x.y;
    #pragma unroll
    for (int m = 1; m < 64; m <<= 1) {
        s  += __shfl_xor(s,  m, 64);
        s2 += __shfl_xor(s2, m, 64);
    }
    __shared__ float sa[4], sb[4];
    const int w = tid >> 6;
    if ((tid & 63) == 0) { sa[w] = s; sb[w] = s2; }
    __syncthreads();
    s  = sa[0] + sa[1] + sa[2] + sa[3];
    s2 = sb[0] + sb[1] + sb[2] + sb[3];

    const float mean = s * (1.0f / D_MODEL);
    const float var  = s2 * (1.0f / D_MODEL) - mean * mean;
    const float rstd = rsqrtf(var + 1e-5f);

    x.x = (x.x - mean) * rstd;
    x.y = (x.y - mean) * rstd;
    *(float2*)&p[tid * 2] = x;
}

// ---------------------------------------------------------------------------
extern "C" void kernel_launch(void* const* d_in, const int* in_sizes, int n_in,
                              void* d_out, int out_size, void* d_ws, size_t ws_size,
                              hipStream_t stream) {
    const float* inQ = (const float*)d_in[0];
    const float* inK = (const float*)d_in[1];
    const float* inV = (const float*)d_in[2];
    const float* WQ  = (const float*)d_in[3];
    const float* WK  = (const float*)d_in[4];
    const float* WV  = (const float*)d_in[5];
    const float* Wfc = (const float*)d_in[6];
    float* out = (float*)d_out;

    bf16* ws = (bf16*)d_ws;
    const size_t WSZ = (size_t)D_MODEL * D_MODEL;       // 262144
    const size_t NE  = (size_t)BATCH * NH * SEQ * 64;   // 4194304
    bf16* Wt   = ws;
    bf16* Qp   = ws + 4 * WSZ;
    bf16* Kp   = Qp + NE;
    bf16* Vp   = Kp + NE;
    bf16* ctxb = Vp + NE;

    wconv<<<dim3(8, 8, 4), 256, 0, stream>>>(WQ, WK, WV, Wfc, Wt);
    proj_mfma<<<dim3(ROWS / 128, D_MODEL / 128, 3), 512, 0, stream>>>(
        inQ, inK, inV, Wt, Qp, Kp, Vp);
    attn_mfma<<<dim3(SEQ / 64, BATCH * NH), 256, 0, stream>>>(Qp, Kp, Vp, ctxb);
    fc_mfma<<<dim3(ROWS / 128, D_MODEL / 128), 512, 0, stream>>>(
        ctxb, Wt + 3 * WSZ, inQ, out);
    ln_kernel<<<ROWS, 256, 0, stream>>>(out);
}

// Round 10
// 165.829 us; speedup vs baseline: 1.1615x; 1.0187x over previous
//
#include <hip/hip_runtime.h>
#include <hip/hip_bf16.h>

#define D_MODEL 512
#define NH      8
#define SEQ     2048
#define BATCH   4
#define WINDOW  256
#define ROWS    (BATCH*SEQ)   // 8192

typedef __attribute__((ext_vector_type(8))) short bf16x8;
typedef __attribute__((ext_vector_type(4))) float f32x4;
typedef __hip_bfloat16 bf16;

__device__ __forceinline__ f32x4 mfma16(bf16x8 a, bf16x8 b, f32x4 c) {
    return __builtin_amdgcn_mfma_f32_16x16x32_bf16(a, b, c, 0, 0, 0);
}

__device__ __forceinline__ void gload16(const void* g, void* l) {
    __builtin_amdgcn_global_load_lds((const __attribute__((address_space(1))) void*)g,
                                     (__attribute__((address_space(3))) void*)l, 16, 0, 0);
}

__device__ __forceinline__ unsigned pack2(float lo, float hi) {
    float2 t; t.x = lo; t.y = hi;
    __hip_bfloat162 h = __float22bfloat162_rn(t);
    return *(unsigned*)&h;
}

// ---------------------------------------------------------------------------
// xconv: X f32 [8192][512] -> bf16 [8192][512]  (3 inputs via blockIdx.y)
// ---------------------------------------------------------------------------
__global__ __launch_bounds__(256)
void xconv(const float* __restrict__ Xq, const float* __restrict__ Xk,
           const float* __restrict__ Xv, bf16* __restrict__ Xb) {
    const int z = blockIdx.y;
    const float* src = (z == 0) ? Xq : (z == 1) ? Xk : Xv;
    bf16* dst = Xb + (size_t)z * ROWS * D_MODEL;

    const int idx = blockIdx.x * 256 + threadIdx.x;     // chunk of 8 floats
    const float4 f0 = ((const float4*)src)[idx * 2];
    const float4 f1 = ((const float4*)src)[idx * 2 + 1];
    int4 pk;
    pk.x = pack2(f0.x, f0.y);
    pk.y = pack2(f0.z, f0.w);
    pk.z = pack2(f1.x, f1.y);
    pk.w = pack2(f1.z, f1.w);
    ((int4*)dst)[idx] = pk;
}

// ---------------------------------------------------------------------------
// W transpose+convert: W[512k][512n] f32 -> Wt[512n][512k] bf16 (4 weights)
// ---------------------------------------------------------------------------
__global__ __launch_bounds__(256)
void wconv(const float* __restrict__ W0, const float* __restrict__ W1,
           const float* __restrict__ W2, const float* __restrict__ W3,
           bf16* __restrict__ Wt) {
    const int z = blockIdx.z;
    const float* W = (z == 0) ? W0 : (z == 1) ? W1 : (z == 2) ? W2 : W3;
    bf16* dst = Wt + (size_t)z * D_MODEL * D_MODEL;

    __shared__ float t[64][65];
    const int k0 = blockIdx.x * 64, n0 = blockIdx.y * 64;
    const int tid = threadIdx.x;

    #pragma unroll
    for (int i = 0; i < 16; ++i) {
        const int e = tid + 256 * i, r = e >> 6, c = e & 63;
        t[r][c] = W[(size_t)(k0 + r) * D_MODEL + n0 + c];
    }
    __syncthreads();
    #pragma unroll
    for (int i = 0; i < 16; ++i) {
        const int e = tid + 256 * i, r = e >> 6, c = e & 63;
        dst[(size_t)(n0 + r) * D_MODEL + k0 + c] = __float2bfloat16(t[c][r]);
    }
}

// ---------------------------------------------------------------------------
// GEMM core: 128x128 tile, BK=32, ring-3 LDS (48KB), counted vmcnt, 512 thr.
// Both operands bf16 row-major [.][512] via gload_lds with pre-swizzled src.
// slot swizzle: s ^ ((row>>1)&3)  -> 2-way bank aliasing only (free).
// ---------------------------------------------------------------------------
__global__ __launch_bounds__(512)
void proj_mfma(const bf16* __restrict__ Xb, const bf16* __restrict__ Wt,
               bf16* __restrict__ Qp, bf16* __restrict__ Kp, bf16* __restrict__ Vp) {
    const int z = blockIdx.z;
    const bf16* X = Xb + (size_t)z * ROWS * D_MODEL;      // [8192][512] bf16
    const bf16* W = Wt + (size_t)z * D_MODEL * D_MODEL;   // [n][k] bf16
    bf16* outp = (z == 0) ? Qp : (z == 1) ? Kp : Vp;

    __shared__ bf16 As[3][128 * 32];
    __shared__ bf16 Bs[3][128 * 32];

    const int tid = threadIdx.x;
    const int lane = tid & 63, w = tid >> 6;
    const int wr = w >> 2, wc = w & 3;          // 2 x 4 wave grid
    const int row0 = blockIdx.x * 128, col0 = blockIdx.y * 128;
    const int g = lane >> 4, m16 = lane & 15;

    f32x4 acc[4][2] = {};

    const int sn = tid >> 2, ss = tid & 3;
    const int soff = (ss ^ ((sn >> 1) & 3)) * 8;

    auto stage = [&](int buf, int t) {
        const int k0 = t * 32;
        gload16(X + (size_t)(row0 + sn) * D_MODEL + k0 + soff, &As[buf][tid * 8]);
        gload16(W + (size_t)(col0 + sn) * D_MODEL + k0 + soff, &Bs[buf][tid * 8]);
    };
    auto compute = [&](int buf) {
        bf16x8 af[4], bfr[2];
        #pragma unroll
        for (int mi = 0; mi < 4; ++mi) {
            const int m = wr * 64 + mi * 16 + m16;
            af[mi] = *(const bf16x8*)&As[buf][m * 32 + ((g ^ ((m >> 1) & 3)) * 8)];
        }
        #pragma unroll
        for (int ni = 0; ni < 2; ++ni) {
            const int n = wc * 32 + ni * 16 + m16;
            bfr[ni] = *(const bf16x8*)&Bs[buf][n * 32 + ((g ^ ((n >> 1) & 3)) * 8)];
        }
        #pragma unroll
        for (int mi = 0; mi < 4; ++mi)
            #pragma unroll
            for (int ni = 0; ni < 2; ++ni)
                acc[mi][ni] = mfma16(af[mi], bfr[ni], acc[mi][ni]);
    };

    stage(0, 0);
    stage(1, 1);

    int ib = 0;
    #pragma unroll 1
    for (int t = 0; t < 15; ++t) {
        asm volatile("s_waitcnt vmcnt(2)" ::: "memory");   // tile t landed
        __builtin_amdgcn_s_barrier();
        __builtin_amdgcn_sched_barrier(0);
        if (t + 2 < 16) {
            const int nb = (ib + 2 >= 3) ? ib - 1 : ib + 2;
            stage(nb, t + 2);
        }
        compute(ib);
        ib = (ib + 1 == 3) ? 0 : ib + 1;
    }
    asm volatile("s_waitcnt vmcnt(0)" ::: "memory");
    __builtin_amdgcn_s_barrier();
    __builtin_amdgcn_sched_barrier(0);
    compute(ib);

    if (z < 2) {
        #pragma unroll
        for (int mi = 0; mi < 4; ++mi)
            #pragma unroll
            for (int ni = 0; ni < 2; ++ni) {
                const int c = col0 + wc * 32 + ni * 16 + m16;
                const int h = c >> 6, d = c & 63;
                #pragma unroll
                for (int reg = 0; reg < 4; ++reg) {
                    const int r = row0 + wr * 64 + mi * 16 + g * 4 + reg;
                    const int b = r >> 11, l = r & (SEQ - 1);
                    outp[(((size_t)b * NH + h) * SEQ + l) * 64 + d] =
                        __float2bfloat16(acc[mi][ni][reg]);
                }
            }
    } else {
        #pragma unroll
        for (int mi = 0; mi < 4; ++mi)
            #pragma unroll
            for (int ni = 0; ni < 2; ++ni) {
                const int c = col0 + wc * 32 + ni * 16 + m16;
                const int h = c >> 6, d = c & 63;
                const int r = row0 + wr * 64 + mi * 16 + g * 4;
                const int b = r >> 11, l = r & (SEQ - 1);
                uint2 pv;
                pv.x = pack2(acc[mi][ni][0], acc[mi][ni][1]);
                pv.y = pack2(acc[mi][ni][2], acc[mi][ni][3]);
                *(uint2*)&outp[(((size_t)b * NH + h) * 64 + d) * SEQ + l] = pv;
            }
    }
}

// ---------------------------------------------------------------------------
// Banded flash attention (round-6 measured version, unchanged)
// ---------------------------------------------------------------------------
__global__ __launch_bounds__(256)
void attn_mfma(const bf16* __restrict__ Qp, const bf16* __restrict__ Kp,
               const bf16* __restrict__ Vp, bf16* __restrict__ ctx) {
    __shared__ bf16 QP[64 * 64];        // Q staging, then P (per-wave regions)
    __shared__ bf16 Ks[2][64 * 64];
    __shared__ bf16 Vt[2][64 * 64];

    const int bh = blockIdx.y, b = bh >> 3, h = bh & 7;
    const int q0 = blockIdx.x * 64;
    const int tid = threadIdx.x;
    const int lane = tid & 63, w = tid >> 6;
    const int g = lane >> 4, m16 = lane & 15;

    const size_t kvbase = (size_t)bh * SEQ * 64;   // Qp/Kp [bh][l][64]
    const size_t vtbase = (size_t)bh * 64 * SEQ;   // Vp    [bh][d][l]

    auto stageKV = [&](int buf, int k0) {
        #pragma unroll
        for (int i = 0; i < 2; ++i) {
            const int chunk = i * 256 + tid;
            const int r = chunk >> 3, s = chunk & 7;
            gload16(Kp + kvbase + (size_t)(k0 + r) * 64 + ((s ^ (r & 7)) * 8),
                    &Ks[buf][(i * 256 + w * 64) * 8]);
            gload16(Vp + vtbase + (size_t)r * SEQ + k0 + ((s ^ (r & 7)) * 8),
                    &Vt[buf][(i * 256 + w * 64) * 8]);
        }
    };

    int klo = q0 - (WINDOW - 1); if (klo < 0) klo = 0;
    const int kt0 = klo >> 6, kt1 = q0 >> 6;

    #pragma unroll
    for (int i = 0; i < 2; ++i) {
        const int chunk = i * 256 + tid;
        const int r = chunk >> 3, s = chunk & 7;
        gload16(Qp + kvbase + (size_t)(q0 + r) * 64 + ((s ^ (r & 7)) * 8),
                &QP[(i * 256 + w * 64) * 8]);
    }
    stageKV(0, kt0 * 64);
    __syncthreads();

    bf16x8 qf[2];
    #pragma unroll
    for (int c = 0; c < 2; ++c) {
        const int r = w * 16 + m16;
        qf[c] = *(const bf16x8*)&QP[r * 64 + (((c * 4 + g) ^ (m16 & 7)) * 8)];
    }

    f32x4 o[4] = {};
    float rs = 0.f;
    const int qg = q0 + w * 16 + m16;

    int cur = 0;
    for (int kt = kt0; kt <= kt1; ++kt) {
        const int k0 = kt * 64;
        if (kt < kt1) stageKV(cur ^ 1, (kt + 1) * 64);

        f32x4 st[4] = {};
        #pragma unroll
        for (int c = 0; c < 2; ++c) {
            bf16x8 kf[4];
            #pragma unroll
            for (int f = 0; f < 4; ++f) {
                const int r = f * 16 + m16;
                kf[f] = *(const bf16x8*)&Ks[cur][r * 64 + (((c * 4 + g) ^ (m16 & 7)) * 8)];
            }
            #pragma unroll
            for (int f = 0; f < 4; ++f)
                st[f] = mfma16(kf[f], qf[c], st[f]);
        }

        const int masktype = (k0 == q0) ? 1 : ((k0 < q0 - 192) ? 2 : 0);
        #pragma unroll
        for (int f = 0; f < 4; ++f) {
            float p[4];
            #pragma unroll
            for (int reg = 0; reg < 4; ++reg) {
                const int kg = k0 + f * 16 + g * 4 + reg;
                bool valid = (masktype == 0) || (masktype == 1 ? (kg <= qg)
                                                              : (kg >= qg - (WINDOW - 1)));
                p[reg] = valid ? __expf(st[f][reg] * 0.125f) : 0.f;
                rs += p[reg];
            }
            uint2 pkv;
            pkv.x = pack2(p[0], p[1]);
            pkv.y = pack2(p[2], p[3]);
            const int slot = (f * 2 + (g >> 1)) ^ (m16 & 7);
            *(uint2*)&QP[w * 1024 + m16 * 64 + slot * 8 + (g & 1) * 4] = pkv;
        }

        #pragma unroll
        for (int c = 0; c < 2; ++c) {
            const bf16x8 pf =
                *(const bf16x8*)&QP[w * 1024 + m16 * 64 + (((c * 4 + g) ^ (m16 & 7)) * 8)];
            #pragma unroll
            for (int f2 = 0; f2 < 4; ++f2) {
                const int r = f2 * 16 + m16;
                const bf16x8 vf =
                    *(const bf16x8*)&Vt[cur][r * 64 + (((c * 4 + g) ^ (m16 & 7)) * 8)];
                o[f2] = mfma16(pf, vf, o[f2]);
            }
        }

        if (kt < kt1) __syncthreads();
        cur ^= 1;
    }

    rs += __shfl_xor(rs, 16, 64);
    rs += __shfl_xor(rs, 32, 64);
    const float inv = 1.0f / rs;
    float invr[4];
    #pragma unroll
    for (int reg = 0; reg < 4; ++reg)
        invr[reg] = __shfl(inv, g * 4 + reg, 64);

    #pragma unroll
    for (int f2 = 0; f2 < 4; ++f2) {
        const int d = f2 * 16 + m16;
        #pragma unroll
        for (int reg = 0; reg < 4; ++reg) {
            const int qrow = w * 16 + g * 4 + reg;
            ctx[((size_t)b * SEQ + q0 + qrow) * D_MODEL + h * 64 + d] =
                __float2bfloat16(o[f2][reg] * invr[reg]);
        }
    }
}

// ---------------------------------------------------------------------------
// fc GEMM: same ring-3 counted-vmcnt core; ctx bf16 @ Wfc^T + resid -> f32
// ---------------------------------------------------------------------------
__global__ __launch_bounds__(512)
void fc_mfma(const bf16* __restrict__ ctx, const bf16* __restrict__ Wt,
             const float* __restrict__ resid, float* __restrict__ out) {
    __shared__ bf16 As[3][128 * 32];
    __shared__ bf16 Bs[3][128 * 32];

    const int tid = threadIdx.x;
    const int lane = tid & 63, w = tid >> 6;
    const int wr = w >> 2, wc = w & 3;
    const int row0 = blockIdx.x * 128, col0 = blockIdx.y * 128;
    const int g = lane >> 4, m16 = lane & 15;

    f32x4 acc[4][2] = {};

    const int sn = tid >> 2, ss = tid & 3;
    const int soff = (ss ^ ((sn >> 1) & 3)) * 8;

    auto stage = [&](int buf, int t) {
        const int k0 = t * 32;
        gload16(ctx + (size_t)(row0 + sn) * D_MODEL + k0 + soff, &As[buf][tid * 8]);
        gload16(Wt + (size_t)(col0 + sn) * D_MODEL + k0 + soff, &Bs[buf][tid * 8]);
    };
    auto compute = [&](int buf) {
        bf16x8 af[4], bfr[2];
        #pragma unroll
        for (int mi = 0; mi < 4; ++mi) {
            const int m = wr * 64 + mi * 16 + m16;
            af[mi] = *(const bf16x8*)&As[buf][m * 32 + ((g ^ ((m >> 1) & 3)) * 8)];
        }
        #pragma unroll
        for (int ni = 0; ni < 2; ++ni) {
            const int n = wc * 32 + ni * 16 + m16;
            bfr[ni] = *(const bf16x8*)&Bs[buf][n * 32 + ((g ^ ((n >> 1) & 3)) * 8)];
        }
        #pragma unroll
        for (int mi = 0; mi < 4; ++mi)
            #pragma unroll
            for (int ni = 0; ni < 2; ++ni)
                acc[mi][ni] = mfma16(af[mi], bfr[ni], acc[mi][ni]);
    };

    stage(0, 0);
    stage(1, 1);

    int ib = 0;
    #pragma unroll 1
    for (int t = 0; t < 15; ++t) {
        asm volatile("s_waitcnt vmcnt(2)" ::: "memory");
        __builtin_amdgcn_s_barrier();
        __builtin_amdgcn_sched_barrier(0);
        if (t + 2 < 16) {
            const int nb = (ib + 2 >= 3) ? ib - 1 : ib + 2;
            stage(nb, t + 2);
        }
        compute(ib);
        ib = (ib + 1 == 3) ? 0 : ib + 1;
    }
    asm volatile("s_waitcnt vmcnt(0)" ::: "memory");
    __builtin_amdgcn_s_barrier();
    __builtin_amdgcn_sched_barrier(0);
    compute(ib);

    #pragma unroll
    for (int mi = 0; mi < 4; ++mi)
        #pragma unroll
        for (int ni = 0; ni < 2; ++ni) {
            const int c = col0 + wc * 32 + ni * 16 + m16;
            #pragma unroll
            for (int reg = 0; reg < 4; ++reg) {
                const int r = row0 + wr * 64 + mi * 16 + g * 4 + reg;
                out[(size_t)r * D_MODEL + c] = acc[mi][ni][reg] + resid[(size_t)r * D_MODEL + c];
            }
        }
}

// ---------------------------------------------------------------------------
// LayerNorm in-place over last dim (512)
// ---------------------------------------------------------------------------
__global__ __launch_bounds__(256)
void ln_kernel(float* __restrict__ out) {
    const int row = blockIdx.x;
    float* p = out + (size_t)row * D_MODEL;
    const int tid = threadIdx.x;

    float2 x = *(float2*)&p[tid * 2];
    float s  = x.x + x.y;
    float s2 = x.x * x.x + x.y * x.y;
    #pragma unroll
    for (int m = 1; m < 64; m <<= 1) {
        s  += __shfl_xor(s,  m, 64);
        s2 += __shfl_xor(s2, m, 64);
    }
    __shared__ float sa[4], sb[4];
    const int w = tid >> 6;
    if ((tid & 63) == 0) { sa[w] = s; sb[w] = s2; }
    __syncthreads();
    s  = sa[0] + sa[1] + sa[2] + sa[3];
    s2 = sb[0] + sb[1] + sb[2] + sb[3];

    const float mean = s * (1.0f / D_MODEL);
    const float var  = s2 * (1.0f / D_MODEL) - mean * mean;
    const float rstd = rsqrtf(var + 1e-5f);

    x.x = (x.x - mean) * rstd;
    x.y = (x.y - mean) * rstd;
    *(float2*)&p[tid * 2] = x;
}

// ---------------------------------------------------------------------------
extern "C" void kernel_launch(void* const* d_in, const int* in_sizes, int n_in,
                              void* d_out, int out_size, void* d_ws, size_t ws_size,
                              hipStream_t stream) {
    const float* inQ = (const float*)d_in[0];
    const float* inK = (const float*)d_in[1];
    const float* inV = (const float*)d_in[2];
    const float* WQ  = (const float*)d_in[3];
    const float* WK  = (const float*)d_in[4];
    const float* WV  = (const float*)d_in[5];
    const float* Wfc = (const float*)d_in[6];
    float* out = (float*)d_out;

    bf16* ws = (bf16*)d_ws;
    const size_t WSZ = (size_t)D_MODEL * D_MODEL;       // 262144
    const size_t NE  = (size_t)BATCH * NH * SEQ * 64;   // 4194304 (= ROWS*D_MODEL)
    bf16* Wt   = ws;                   // 4 * WSZ
    bf16* Xb   = ws + 4 * WSZ;         // 3 * NE
    bf16* Qp   = Xb + 3 * NE;
    bf16* Kp   = Qp + NE;
    bf16* Vp   = Kp + NE;
    bf16* ctxb = Vp + NE;

    xconv<<<dim3(ROWS * D_MODEL / (256 * 8), 3), 256, 0, stream>>>(inQ, inK, inV, Xb);
    wconv<<<dim3(8, 8, 4), 256, 0, stream>>>(WQ, WK, WV, Wfc, Wt);
    proj_mfma<<<dim3(ROWS / 128, D_MODEL / 128, 3), 512, 0, stream>>>(
        Xb, Wt, Qp, Kp, Vp);
    attn_mfma<<<dim3(SEQ / 64, BATCH * NH), 256, 0, stream>>>(Qp, Kp, Vp, ctxb);
    fc_mfma<<<dim3(ROWS / 128, D_MODEL / 128), 512, 0, stream>>>(
        ctxb, Wt + 3 * WSZ, inQ, out);
    ln_kernel<<<ROWS, 256, 0, stream>>>(out);
}